// Round 5
// baseline (275.143 us; speedup 1.0000x reference)
//
#include <hip/hip_runtime.h>

// Problem constants
constexpr int N = 16, C = 64, H = 128, W = 128, P = H * W;   // P = 16384
constexpr int NL = 256, PK = 1024;                            // 256 windows, 32x32 each

// Workspace layout (float units). Liveness:
//   RA: prb bf16 [nl][64cc][1024px]   (k3 -> k5)
//   RB: x1t bf16 [n][px][64c]         (k1 -> k3)
//   RC: x2t bf16 [n][px][64c]         (k1 -> k5)
constexpr size_t OFF_RA   = 0;
constexpr size_t OFF_RB   = 8388608;
constexpr size_t OFF_RC   = 16777216;
constexpr size_t OFF_SUMS = 25165824;            // 16384 fp32
constexpr size_t OFF_WMOD = OFF_SUMS + 16384;    // 36864 ush
constexpr size_t OFF_W3L  = OFF_WMOD + 18432;    // 8192 ush

typedef short bf16x8 __attribute__((ext_vector_type(8)));
typedef float f32x4  __attribute__((ext_vector_type(4)));

__device__ inline unsigned short f2bf(float f) {
    unsigned u = __float_as_uint(f);
    unsigned r = (u + 0x7FFFu + ((u >> 16) & 1u)) >> 16;
    return (unsigned short)r;
}
__device__ inline float bf2f(unsigned short h) {
    return __uint_as_float(((unsigned)h) << 16);
}

// ---------------------------------------------------------------------------
// K1: conv1 (1x1, 64->128) + bias via bf16 MFMA, NO LDS.
// B-fragments loaded directly from x (global, 8 strided scalars -> cvt);
// A-fragments built inline from L1-hot conv1_w. Wave: 32 px x 128 co.
// Blocks >= 2048 instead run the weight-prep (wmod, w3lay) + sums zeroing.
__global__ __launch_bounds__(256) void k1_conv1(const float* __restrict__ x,
                                                const float* __restrict__ w1,
                                                const float* __restrict__ b1,
                                                const float* __restrict__ pos_w,
                                                const float* __restrict__ conv2_w,
                                                const float* __restrict__ w3,
                                                unsigned short* __restrict__ x1t,
                                                unsigned short* __restrict__ x2t,
                                                unsigned short* __restrict__ wmod,
                                                unsigned short* __restrict__ w3lay,
                                                float* __restrict__ sums) {
    int bid = blockIdx.x;
    int t   = threadIdx.x;
    if (bid >= 2048) {
        // prep role: 61440 elements = 36864 wmod + 8192 w3lay + 16384 sums
        for (int u = (bid - 2048) * 256 + t; u < 61440; u += 8192) {
            if (u < 36864) {               // wmod[tap][cib][64co][32ci]
                int cir = u & 31, co = (u >> 5) & 63, cib = (u >> 11) & 1, tap = u >> 12;
                int ci = cib * 32 + cir;
                float v = pos_w[(co * 64 + ci) * 9 + tap];
                if (tap == 4) v += conv2_w[co * 64 + ci];
                wmod[u] = f2bf(v);
            } else if (u < 45056) {        // w3lay[cib(4)][64co][32ci]
                int q = u - 36864;
                int cir = q & 31, co = (q >> 5) & 63, cib = q >> 11;
                w3lay[q] = f2bf(w3[co * 128 + cib * 32 + cir]);
            } else {
                sums[u - 45056] = 0.f;
            }
        }
        return;
    }
    int n    = bid >> 7;
    int wave = t >> 6, lane = t & 63;
    int quad = lane >> 4, l16 = lane & 15;
    int px0  = (bid & 127) * 128 + wave * 32;
    const float* xb = x + (size_t)n * 64 * P;
    f32x4 acc[8][2] = {};
    #pragma unroll
    for (int cib = 0; cib < 2; ++cib) {
        bf16x8 bfr[2];
        #pragma unroll
        for (int pt = 0; pt < 2; ++pt) {
            int px = px0 + pt * 16 + l16;
            unsigned short tmp[8];
            #pragma unroll
            for (int j = 0; j < 8; ++j)
                tmp[j] = f2bf(xb[(size_t)(cib * 32 + quad * 8 + j) * P + px]);
            bfr[pt] = *(bf16x8*)tmp;
        }
        #pragma unroll
        for (int ct = 0; ct < 8; ++ct) {
            const float* wr = w1 + (ct * 16 + l16) * 64 + cib * 32 + quad * 8;
            float4 wa = *(const float4*)wr;
            float4 wb = *(const float4*)(wr + 4);
            unsigned short wt[8];
            wt[0] = f2bf(wa.x); wt[1] = f2bf(wa.y); wt[2] = f2bf(wa.z); wt[3] = f2bf(wa.w);
            wt[4] = f2bf(wb.x); wt[5] = f2bf(wb.y); wt[6] = f2bf(wb.z); wt[7] = f2bf(wb.w);
            bf16x8 af = *(bf16x8*)wt;
            acc[ct][0] = __builtin_amdgcn_mfma_f32_16x16x32_bf16(af, bfr[0], acc[ct][0], 0, 0, 0);
            acc[ct][1] = __builtin_amdgcn_mfma_f32_16x16x32_bf16(af, bfr[1], acc[ct][1], 0, 0, 0);
        }
    }
    #pragma unroll
    for (int ct = 0; ct < 8; ++ct) {
        int co0 = ct * 16 + quad * 4;
        float4 bb = *(const float4*)(b1 + co0);
        #pragma unroll
        for (int pt = 0; pt < 2; ++pt) {
            int px = px0 + pt * 16 + l16;
            ushort4 o;
            o.x = f2bf(acc[ct][pt][0] + bb.x);
            o.y = f2bf(acc[ct][pt][1] + bb.y);
            o.z = f2bf(acc[ct][pt][2] + bb.z);
            o.w = f2bf(acc[ct][pt][3] + bb.w);
            if (co0 < 64)
                *(ushort4*)(x1t + ((size_t)n * P + px) * 64 + co0) = o;
            else
                *(ushort4*)(x2t + ((size_t)n * P + px) * 64 + (co0 - 64)) = o;
        }
    }
}

// ---------------------------------------------------------------------------
// K3: fused adaptive-pool + 3x3 SAME conv (conv2 folded) + biases via MFMA.
// Block: one window, 8 pr-rows. SINGLE staging phase (both 32-ci planes),
// one barrier. LDS 2 planes x 340px x 32ush, XOR-swizzled (validated R4):
// 43.5 KB => 3 blocks/CU so staging overlaps other blocks' compute.
__global__ __launch_bounds__(256) void k3_pool_pr(const unsigned short* __restrict__ x1t,
                                                  const unsigned short* __restrict__ wmod,
                                                  const float* __restrict__ b2,
                                                  const float* __restrict__ posb,
                                                  unsigned short* __restrict__ prb,
                                                  float* __restrict__ sums) {
    __shared__ __align__(16) unsigned short lxs[2 * 340 * 32];  // 43520 B
    int bid = blockIdx.x;
    int nl  = bid >> 2;
    int r0  = (bid & 3) * 8;
    int n   = nl >> 4, wl = nl & 15;
    int wi  = wl >> 2, wj = wl & 3;
    int t   = threadIdx.x;
    const unsigned short* xb = x1t + (size_t)n * P * 64;
    // ---- stage: 2720 chunks = 2 planes x 340 px x 4 parts of 16 B ----
    for (int it = 0; it < 11; ++it) {
        int e = t + it * 256;
        if (e < 2720) {
            int part = e & 3;
            int u    = e >> 2;                  // 0..679
            int cib  = (u >= 340);
            int pix  = u - cib * 340;
            int lr = pix / 34, lc = pix - lr * 34;
            int gr = r0 - 1 + lr, gc = lc - 1;
            unsigned short oc[8];
            if ((unsigned)gr < 32u && (unsigned)gc < 32u) {
                int sh = gr + (gr >> 4), sw = gc + (gc >> 4);
                int uu = wi * 34 + sh - 4, vv = wj * 34 + sw - 4;
                int ra = min(max(uu, 0), 127), rb = min(max(uu + 1, 0), 127);
                int ca = min(max(vv, 0), 127), cb = min(max(vv + 1, 0), 127);
                int off = cib * 32 + part * 8;
                uint4 A  = *(const uint4*)(xb + (size_t)(ra * 128 + ca) * 64 + off);
                uint4 B  = *(const uint4*)(xb + (size_t)(ra * 128 + cb) * 64 + off);
                uint4 Cc = *(const uint4*)(xb + (size_t)(rb * 128 + ca) * 64 + off);
                uint4 D  = *(const uint4*)(xb + (size_t)(rb * 128 + cb) * 64 + off);
                const unsigned short* a = (const unsigned short*)&A;
                const unsigned short* b = (const unsigned short*)&B;
                const unsigned short* c = (const unsigned short*)&Cc;
                const unsigned short* d = (const unsigned short*)&D;
                #pragma unroll
                for (int q = 0; q < 8; ++q)
                    oc[q] = f2bf(0.25f * (bf2f(a[q]) + bf2f(b[q]) + bf2f(c[q]) + bf2f(d[q])));
            } else {
                #pragma unroll
                for (int q = 0; q < 8; ++q) oc[q] = 0;
            }
            *(uint4*)(lxs + cib * 10880 + pix * 32 + ((part ^ ((pix >> 1) & 3)) * 8)) = *(const uint4*)oc;
        }
    }
    __syncthreads();
    // ---- compute: 9 taps x 2 cib x 16 MFMA per wave ----
    int wave = t >> 6, lane = t & 63;
    int quad = lane >> 4, l16 = lane & 15;
    int wrow0 = wave * 2;
    f32x4 acc[4][4] = {};
    #pragma unroll
    for (int tap = 0; tap < 9; ++tap) {
        int dh = tap / 3, dw = tap % 3;
        #pragma unroll
        for (int cib = 0; cib < 2; ++cib) {
            bf16x8 af[4], bfr[4];
            #pragma unroll
            for (int ct = 0; ct < 4; ++ct)
                af[ct] = *(const bf16x8*)(wmod + (((tap * 2 + cib) * 64) + ct * 16 + l16) * 32 + quad * 8);
            #pragma unroll
            for (int pt = 0; pt < 4; ++pt) {
                int pix = (wrow0 + (pt >> 1) + dh) * 34 + ((pt & 1) * 16 + l16 + dw);
                bfr[pt] = *(const bf16x8*)(lxs + cib * 10880 + pix * 32 + ((quad ^ ((pix >> 1) & 3)) * 8));
            }
            #pragma unroll
            for (int ct = 0; ct < 4; ++ct)
                #pragma unroll
                for (int pt = 0; pt < 4; ++pt)
                    acc[ct][pt] = __builtin_amdgcn_mfma_f32_16x16x32_bf16(af[ct], bfr[pt], acc[ct][pt], 0, 0, 0);
        }
    }
    // epilogue: bias, prb write (bf16), SE partial sums
    #pragma unroll
    for (int ct = 0; ct < 4; ++ct) {
        #pragma unroll
        for (int r = 0; r < 4; ++r) {
            int co = ct * 16 + quad * 4 + r;
            float bias = b2[co] + posb[co];
            float s = 0.f;
            #pragma unroll
            for (int pt = 0; pt < 4; ++pt) {
                float v = acc[ct][pt][r] + bias;
                int row = r0 + wrow0 + (pt >> 1);
                int col = (pt & 1) * 16 + l16;
                prb[(size_t)nl * 65536 + co * 1024 + row * 32 + col] = f2bf(v);
                s += v;
            }
            s += __shfl_xor(s, 1);
            s += __shfl_xor(s, 2);
            s += __shfl_xor(s, 4);
            s += __shfl_xor(s, 8);
            if (l16 == 0) atomicAdd(&sums[nl * 64 + co], s);
        }
    }
}

// ---------------------------------------------------------------------------
// K5: fused SE-MLP + unscramble-gather + conv3 (1x1, 128->64) + bias, NO LDS
// staging. Block = one W-row (128 px) of image n. Preamble computes the 64
// needed scale values from sums. att B-fragments gathered from prb (scaled
// in-register); x2 B-fragments are native uint4 loads from x2t.
__global__ __launch_bounds__(256) void k5_conv3(const unsigned short* __restrict__ prb,
                                                const float* __restrict__ sums,
                                                const float* __restrict__ se_w1,
                                                const float* __restrict__ se_w2,
                                                const unsigned short* __restrict__ x2t,
                                                const unsigned short* __restrict__ w3lay,
                                                const float* __restrict__ b3,
                                                float* __restrict__ out) {
    __shared__ float shid[16][8];
    __shared__ float sscale[64];
    int bid  = blockIdx.x;
    int n    = bid >> 7;
    int Hrow = bid & 127;
    int h2 = Hrow & 31, ib = Hrow >> 5;
    int t  = threadIdx.x;
    // ---- SE preamble: mean -> 64->8 relu -> 8->64 sigmoid, only needed cc ----
    if (t < 128) {
        int lam = t >> 3, r = t & 7;
        const float* sp = sums + (n * 16 + lam) * 64;
        float s = 0.f;
        #pragma unroll
        for (int ci = 0; ci < 64; ++ci) s += se_w1[r * 64 + ci] * sp[ci];
        shid[lam][r] = fmaxf(s * (1.f / 1024.f), 0.f);
    }
    __syncthreads();
    if (t < 64) {
        int lam = t >> 2, q = t & 3;
        int cc = q * 16 + (h2 >> 1);
        float v = 0.f;
        #pragma unroll
        for (int r = 0; r < 8; ++r) v += se_w2[cc * 8 + r] * shid[lam][r];
        sscale[t] = 1.f + 1.f / (1.f + __expf(-v));   // t == lam*4 + q == c
    }
    __syncthreads();
    int wave = t >> 6, lane = t & 63;
    int quad = lane >> 4, l16 = lane & 15;
    f32x4 acc[4][2] = {};
    // ---- att half (input ch 0..63): gather from prb with scramble+scale ----
    #pragma unroll
    for (int cib = 0; cib < 2; ++cib) {
        bf16x8 bfr[2];
        #pragma unroll
        for (int pt = 0; pt < 2; ++pt) {
            int Wp = wave * 32 + pt * 16 + l16;
            int w2 = Wp & 31, jW = Wp >> 5;
            int hh  = (h2 & 1) * 16 + (w2 >> 1);
            int pix = hh * 32 + (w2 & 1) * 16 + ib * 4 + jW;
            unsigned short tmp[8];
            #pragma unroll
            for (int j = 0; j < 8; ++j) {
                int c  = cib * 32 + quad * 8 + j;
                int nl = n * 16 + (c >> 2);
                int cc = (c & 3) * 16 + (h2 >> 1);
                tmp[j] = f2bf(bf2f(prb[(size_t)nl * 65536 + cc * 1024 + pix]) * sscale[c]);
            }
            bfr[pt] = *(bf16x8*)tmp;
        }
        #pragma unroll
        for (int ct = 0; ct < 4; ++ct) {
            bf16x8 af = *(const bf16x8*)(w3lay + ((size_t)(cib * 64 + ct * 16 + l16)) * 32 + quad * 8);
            #pragma unroll
            for (int pt = 0; pt < 2; ++pt)
                acc[ct][pt] = __builtin_amdgcn_mfma_f32_16x16x32_bf16(af, bfr[pt], acc[ct][pt], 0, 0, 0);
        }
    }
    // ---- x2 half (input ch 64..127): native ci-minor loads ----
    #pragma unroll
    for (int cb = 0; cb < 2; ++cb) {
        bf16x8 bfr[2];
        #pragma unroll
        for (int pt = 0; pt < 2; ++pt) {
            int Wp = wave * 32 + pt * 16 + l16;
            bfr[pt] = *(const bf16x8*)(x2t + ((size_t)n * P + Hrow * 128 + Wp) * 64 + cb * 32 + quad * 8);
        }
        #pragma unroll
        for (int ct = 0; ct < 4; ++ct) {
            bf16x8 af = *(const bf16x8*)(w3lay + ((size_t)((2 + cb) * 64 + ct * 16 + l16)) * 32 + quad * 8);
            #pragma unroll
            for (int pt = 0; pt < 2; ++pt)
                acc[ct][pt] = __builtin_amdgcn_mfma_f32_16x16x32_bf16(af, bfr[pt], acc[ct][pt], 0, 0, 0);
        }
    }
    // ---- epilogue: bias + fp32 out ----
    #pragma unroll
    for (int ct = 0; ct < 4; ++ct) {
        int co0 = ct * 16 + quad * 4;
        float4 bb = *(const float4*)(b3 + co0);
        const float* bp = (const float*)&bb;
        #pragma unroll
        for (int pt = 0; pt < 2; ++pt) {
            int Wp = wave * 32 + pt * 16 + l16;
            #pragma unroll
            for (int r = 0; r < 4; ++r)
                out[((size_t)n * 64 + co0 + r) * P + Hrow * 128 + Wp] = acc[ct][pt][r] + bp[r];
        }
    }
}

// ---------------------------------------------------------------------------
extern "C" void kernel_launch(void* const* d_in, const int* in_sizes, int n_in,
                              void* d_out, int out_size, void* d_ws, size_t ws_size,
                              hipStream_t stream) {
    const float* x       = (const float*)d_in[0];
    const float* conv1_w = (const float*)d_in[1];
    const float* conv1_b = (const float*)d_in[2];
    const float* conv2_w = (const float*)d_in[3];
    const float* conv2_b = (const float*)d_in[4];
    const float* conv3_w = (const float*)d_in[5];
    const float* conv3_b = (const float*)d_in[6];
    const float* pos_w   = (const float*)d_in[7];
    const float* pos_b   = (const float*)d_in[8];
    const float* se_w1   = (const float*)d_in[9];
    const float* se_w2   = (const float*)d_in[10];

    float* ws = (float*)d_ws;
    unsigned short* prb  = (unsigned short*)(ws + OFF_RA);
    unsigned short* x1t  = (unsigned short*)(ws + OFF_RB);
    unsigned short* x2t  = (unsigned short*)(ws + OFF_RC);
    float* sums = ws + OFF_SUMS;
    unsigned short* wmod  = (unsigned short*)(ws + OFF_WMOD);
    unsigned short* w3lay = (unsigned short*)(ws + OFF_W3L);

    k1_conv1  <<<2080, 256, 0, stream>>>(x, conv1_w, conv1_b, pos_w, conv2_w, conv3_w,
                                         x1t, x2t, wmod, w3lay, sums);
    k3_pool_pr<<<1024, 256, 0, stream>>>(x1t, wmod, conv2_b, pos_b, prb, sums);
    k5_conv3  <<<2048, 256, 0, stream>>>(prb, sums, se_w1, se_w2, x2t, w3lay,
                                         conv3_b, (float*)d_out);
}